// Round 2
// baseline (3392.556 us; speedup 1.0000x reference)
//
#include <hip/hip_runtime.h>
#include <hip/hip_bf16.h>
#include <math.h>

// Problem constants
#define B_ 64
#define T_ 50
#define H_ 256
#define G_ 1024
#define V_ 50000

__device__ __forceinline__ float sigm(float x) { return 1.0f / (1.0f + expf(-x)); }

// ---------------------------------------------------------------------------
// Embedding gather: x_tm[t*B + b][h] = emb[idx[b*T + t]][h]   (time-major)
// grid = T*B blocks, 64 threads, one float4 per thread (H=256 = 64*4)
// ---------------------------------------------------------------------------
__global__ __launch_bounds__(64) void embed_k(const int* __restrict__ idx,
                                              const float* __restrict__ emb,
                                              float* __restrict__ x_tm)
{
    const int row = blockIdx.x;          // t*B + b
    const int b = row & (B_ - 1);
    const int t = row >> 6;              // /B_
    const int id = idx[b * T_ + t];
    const float4 v = *reinterpret_cast<const float4*>(emb + (size_t)id * H_ + threadIdx.x * 4);
    *reinterpret_cast<float4*>(x_tm + (size_t)row * H_ + threadIdx.x * 4) = v;
}

// ---------------------------------------------------------------------------
// Tiled fp32 GEMM: C[M][N] = A[M][K] * B + bias
//   B_IS_NK: B is [N][K] (use B^T), else B is [K][N]
// 128x128 tile, 8x8 micro-tile, TK=32. M must be multiple of 128. K mult of 32.
// ---------------------------------------------------------------------------
template<bool B_IS_NK, bool ADD_BIAS>
__global__ __launch_bounds__(256) void gemm128(const float* __restrict__ A,
                                               const float* __restrict__ Bm,
                                               const float* __restrict__ bias,
                                               float* __restrict__ C,
                                               int M, int N, int K)
{
    __shared__ float As[32][132];
    __shared__ float Bs[32][132];

    const int m0 = blockIdx.x * 128;
    const int n0 = blockIdx.y * 128;
    const int tid = threadIdx.x;
    const int tm = (tid >> 4) << 3;   // 0..120
    const int tn = (tid & 15) << 3;   // 0..120

    float acc[8][8];
#pragma unroll
    for (int i = 0; i < 8; ++i)
#pragma unroll
        for (int j = 0; j < 8; ++j) acc[i][j] = 0.0f;

    for (int k0 = 0; k0 < K; k0 += 32) {
        // A tile: 128 rows x 32 k  -> As[k][m]
#pragma unroll
        for (int i = 0; i < 4; ++i) {
            const int s = tid + (i << 8);         // 0..1023
            const int m = s >> 3;                 // 0..127
            const int kk = (s & 7) << 2;          // 0,4,..28
            const float4 v = *reinterpret_cast<const float4*>(
                A + (size_t)(m0 + m) * K + k0 + kk);
            As[kk + 0][m] = v.x; As[kk + 1][m] = v.y;
            As[kk + 2][m] = v.z; As[kk + 3][m] = v.w;
        }
        if (B_IS_NK) {
            // Bm[N][K]: rows are K-contiguous
#pragma unroll
            for (int i = 0; i < 4; ++i) {
                const int s = tid + (i << 8);
                const int n = s >> 3;             // 0..127
                const int kk = (s & 7) << 2;
                float4 v = make_float4(0.f, 0.f, 0.f, 0.f);
                if (n0 + n < N)
                    v = *reinterpret_cast<const float4*>(
                        Bm + (size_t)(n0 + n) * K + k0 + kk);
                Bs[kk + 0][n] = v.x; Bs[kk + 1][n] = v.y;
                Bs[kk + 2][n] = v.z; Bs[kk + 3][n] = v.w;
            }
        } else {
            // Bm[K][N]
#pragma unroll
            for (int i = 0; i < 4; ++i) {
                const int s = tid + (i << 8);
                const int kk = s >> 5;            // 0..31
                const int nn = (s & 31) << 2;     // 0..124
                float4 v = make_float4(0.f, 0.f, 0.f, 0.f);
                if (n0 + nn < N)
                    v = *reinterpret_cast<const float4*>(
                        Bm + (size_t)(k0 + kk) * N + n0 + nn);
                *reinterpret_cast<float4*>(&Bs[kk][nn]) = v;
            }
        }
        __syncthreads();

#pragma unroll
        for (int k = 0; k < 32; ++k) {
            float a[8], bb[8];
            *reinterpret_cast<float4*>(&a[0]) = *reinterpret_cast<const float4*>(&As[k][tm]);
            *reinterpret_cast<float4*>(&a[4]) = *reinterpret_cast<const float4*>(&As[k][tm + 4]);
            *reinterpret_cast<float4*>(&bb[0]) = *reinterpret_cast<const float4*>(&Bs[k][tn]);
            *reinterpret_cast<float4*>(&bb[4]) = *reinterpret_cast<const float4*>(&Bs[k][tn + 4]);
#pragma unroll
            for (int i = 0; i < 8; ++i)
#pragma unroll
                for (int j = 0; j < 8; ++j)
                    acc[i][j] = fmaf(a[i], bb[j], acc[i][j]);
        }
        __syncthreads();
    }

    // epilogue (N multiple of 4 -> per-float4 guard is exact)
#pragma unroll
    for (int i = 0; i < 8; ++i) {
        const int m = m0 + tm + i;
#pragma unroll
        for (int j = 0; j < 8; j += 4) {
            const int n = n0 + tn + j;
            if (n < N) {
                float4 v;
                v.x = acc[i][j + 0] + (ADD_BIAS ? bias[n + 0] : 0.0f);
                v.y = acc[i][j + 1] + (ADD_BIAS ? bias[n + 1] : 0.0f);
                v.z = acc[i][j + 2] + (ADD_BIAS ? bias[n + 2] : 0.0f);
                v.w = acc[i][j + 3] + (ADD_BIAS ? bias[n + 3] : 0.0f);
                *reinterpret_cast<float4*>(C + (size_t)m * N + n) = v;
            }
        }
    }
}

// ---------------------------------------------------------------------------
// MI-LSTM layer 0 step: hh = h_in @ Uh; gates from precomputed xh; update c,h.
// grid = B*4 blocks (b, col-group), 64 threads; thread owns one H-column jl
// and its 4 gate columns {jl, 256+jl, 512+jl, 768+jl}.
// ---------------------------------------------------------------------------
__global__ __launch_bounds__(64) void mi_step_l0(const float* __restrict__ Uh,
                                                 const float* __restrict__ xh_t,
                                                 const float* __restrict__ h_in,
                                                 float* __restrict__ c_io,
                                                 float* __restrict__ h_out,
                                                 const float* __restrict__ alpha,
                                                 const float* __restrict__ b1,
                                                 const float* __restrict__ b2,
                                                 const float* __restrict__ bsv)
{
    const int b = blockIdx.x >> 2;
    const int jl = ((blockIdx.x & 3) << 6) + threadIdx.x;   // 0..255
    const float* __restrict__ hb = h_in + (b << 8);

    float a0 = 0.f, a1 = 0.f, a2 = 0.f, a3 = 0.f;
#pragma unroll 4
    for (int k = 0; k < H_; ++k) {
        const float hk = hb[k];
        const float* u = Uh + k * G_ + jl;
        a0 = fmaf(hk, u[0],   a0);
        a1 = fmaf(hk, u[256], a1);
        a2 = fmaf(hk, u[512], a2);
        a3 = fmaf(hk, u[768], a3);
    }
    const float x0 = xh_t[(b << 10) + jl];
    const float x1 = xh_t[(b << 10) + 256 + jl];
    const float x2 = xh_t[(b << 10) + 512 + jl];
    const float x3 = xh_t[(b << 10) + 768 + jl];

    const float g0 = alpha[jl      ] * x0 * a0 + b1[jl      ] * x0 + b2[jl      ] * a0 + bsv[jl      ];
    const float g1 = alpha[256 + jl] * x1 * a1 + b1[256 + jl] * x1 + b2[256 + jl] * a1 + bsv[256 + jl];
    const float g2 = alpha[512 + jl] * x2 * a2 + b1[512 + jl] * x2 + b2[512 + jl] * a2 + bsv[512 + jl];
    const float g3 = alpha[768 + jl] * x3 * a3 + b1[768 + jl] * x3 + b2[768 + jl] * a3 + bsv[768 + jl];

    const int ci = (b << 8) + jl;
    const float cn = c_io[ci] * sigm(g2 + 1.0f) + sigm(g0) * tanhf(g1);
    c_io[ci] = cn;
    h_out[ci] = tanhf(cn) * sigm(g3);
}

// ---------------------------------------------------------------------------
// MI-LSTM layer 1 step: xh = x_in @ Wx, hh = h_in @ Uh; update c,h; emit output
// (stored batch-major: outs[(b*T + t)*H + jl]).
// ---------------------------------------------------------------------------
__global__ __launch_bounds__(64) void mi_step_l1(const float* __restrict__ Wx,
                                                 const float* __restrict__ Uh,
                                                 const float* __restrict__ x_in,
                                                 const float* __restrict__ h_in,
                                                 float* __restrict__ c_io,
                                                 float* __restrict__ h_out,
                                                 float* __restrict__ outs,
                                                 int t,
                                                 const float* __restrict__ alpha,
                                                 const float* __restrict__ b1,
                                                 const float* __restrict__ b2,
                                                 const float* __restrict__ bsv)
{
    const int b = blockIdx.x >> 2;
    const int jl = ((blockIdx.x & 3) << 6) + threadIdx.x;   // 0..255
    const float* __restrict__ xb = x_in + (b << 8);
    const float* __restrict__ hb = h_in + (b << 8);

    float xa0 = 0.f, xa1 = 0.f, xa2 = 0.f, xa3 = 0.f;
    float ha0 = 0.f, ha1 = 0.f, ha2 = 0.f, ha3 = 0.f;
#pragma unroll 2
    for (int k = 0; k < H_; ++k) {
        const float xk = xb[k];
        const float hk = hb[k];
        const float* w = Wx + k * G_ + jl;
        const float* u = Uh + k * G_ + jl;
        xa0 = fmaf(xk, w[0],   xa0);
        xa1 = fmaf(xk, w[256], xa1);
        xa2 = fmaf(xk, w[512], xa2);
        xa3 = fmaf(xk, w[768], xa3);
        ha0 = fmaf(hk, u[0],   ha0);
        ha1 = fmaf(hk, u[256], ha1);
        ha2 = fmaf(hk, u[512], ha2);
        ha3 = fmaf(hk, u[768], ha3);
    }
    const float g0 = alpha[jl      ] * xa0 * ha0 + b1[jl      ] * xa0 + b2[jl      ] * ha0 + bsv[jl      ];
    const float g1 = alpha[256 + jl] * xa1 * ha1 + b1[256 + jl] * xa1 + b2[256 + jl] * ha1 + bsv[256 + jl];
    const float g2 = alpha[512 + jl] * xa2 * ha2 + b1[512 + jl] * xa2 + b2[512 + jl] * ha2 + bsv[512 + jl];
    const float g3 = alpha[768 + jl] * xa3 * ha3 + b1[768 + jl] * xa3 + b2[768 + jl] * ha3 + bsv[768 + jl];

    const int ci = (b << 8) + jl;
    const float cn = c_io[ci] * sigm(g2 + 1.0f) + sigm(g0) * tanhf(g1);
    c_io[ci] = cn;
    const float hn = tanhf(cn) * sigm(g3);
    h_out[ci] = hn;
    outs[((size_t)(b * T_ + t) << 8) + jl] = hn;
}

// ---------------------------------------------------------------------------
extern "C" void kernel_launch(void* const* d_in, const int* in_sizes, int n_in,
                              void* d_out, int out_size, void* d_ws, size_t ws_size,
                              hipStream_t stream)
{
    const int*   idx   = (const int*)  d_in[0];
    const float* emb   = (const float*)d_in[1];
    const float* Wx    = (const float*)d_in[2];   // [2][256][1024]
    const float* Uh    = (const float*)d_in[3];   // [2][256][1024]
    const float* alpha = (const float*)d_in[4];   // [2][1024]
    const float* b1    = (const float*)d_in[5];
    const float* b2    = (const float*)d_in[6];
    const float* bsv   = (const float*)d_in[7];
    const float* sw    = (const float*)d_in[8];   // [50000][256]
    const float* sb    = (const float*)d_in[9];   // [50000]
    float* out = (float*)d_out;

    // workspace layout (floats); total ~5.0M floats (~20 MB)
    float* ws    = (float*)d_ws;
    float* x_tm  = ws;                       // [T*B][H]      819200
    float* xh0   = x_tm + (size_t)T_ * B_ * H_;       // [T*B][G]  3276800
    float* outs  = xh0 + (size_t)T_ * B_ * G_;        // [B*T][H]   819200
    float* h0a   = outs + (size_t)B_ * T_ * H_;       // 16384 each below
    float* h1a   = h0a + B_ * H_;
    float* c0    = h1a + B_ * H_;
    float* c1    = c0 + B_ * H_;
    float* h0b   = c1 + B_ * H_;
    float* h1b   = h0b + B_ * H_;

    // zero the initial states each call (h0a, h1a, c0, c1 are contiguous)
    hipMemsetAsync(h0a, 0, (size_t)4 * B_ * H_ * sizeof(float), stream);

    // 1) embedding gather (time-major)
    embed_k<<<T_ * B_, 64, 0, stream>>>(idx, emb, x_tm);

    // 2) xh for layer 0, all timesteps at once: [3200,256] @ [256,1024]
    {
        dim3 grid(3200 / 128, G_ / 128);
        gemm128<false, false><<<grid, 256, 0, stream>>>(x_tm, Wx, nullptr, xh0,
                                                        3200, G_, H_);
    }

    // 3) recurrence
    const float* Wx1 = Wx + (size_t)H_ * G_;
    const float* Uh0 = Uh;
    const float* Uh1 = Uh + (size_t)H_ * G_;
    for (int t = 0; t < T_; ++t) {
        const float* h0_in = (t & 1) ? h0b : h0a;
        float*       h0_out = (t & 1) ? h0a : h0b;
        const float* h1_in = (t & 1) ? h1b : h1a;
        float*       h1_out = (t & 1) ? h1a : h1b;
        mi_step_l0<<<B_ * 4, 64, 0, stream>>>(Uh0, xh0 + (size_t)t * B_ * G_,
                                              h0_in, c0, h0_out,
                                              alpha, b1, b2, bsv);
        mi_step_l1<<<B_ * 4, 64, 0, stream>>>(Wx1, Uh1, h0_out, h1_in, c1, h1_out,
                                              outs, t,
                                              alpha + G_, b1 + G_, b2 + G_, bsv + G_);
    }

    // 4) logits = outs @ sw^T + sb : [3200,256] @ [50000,256]^T
    {
        dim3 grid(3200 / 128, (V_ + 127) / 128);
        gemm128<true, true><<<grid, 256, 0, stream>>>(outs, sw, sb, out,
                                                      3200, V_, H_);
    }
}

// Round 3
// 1759.417 us; speedup vs baseline: 1.9282x; 1.9282x over previous
//
#include <hip/hip_runtime.h>
#include <hip/hip_bf16.h>
#include <math.h>

// Problem constants
#define B_ 64
#define T_ 50
#define H_ 256
#define G_ 1024
#define V_ 50000

using f16x8 = __attribute__((ext_vector_type(8))) _Float16;
using f32x4 = __attribute__((ext_vector_type(4))) float;

__device__ __forceinline__ float sigm(float x) { return 1.0f / (1.0f + expf(-x)); }

// ---------------------------------------------------------------------------
// Embedding gather: x_tm[t*B + b][h] = emb[idx[b*T + t]][h]   (time-major)
// ---------------------------------------------------------------------------
__global__ __launch_bounds__(64) void embed_k(const int* __restrict__ idx,
                                              const float* __restrict__ emb,
                                              float* __restrict__ x_tm)
{
    const int row = blockIdx.x;          // t*B + b
    const int b = row & (B_ - 1);
    const int t = row >> 6;              // /B_
    const int id = idx[b * T_ + t];
    const float4 v = *reinterpret_cast<const float4*>(emb + (size_t)id * H_ + threadIdx.x * 4);
    *reinterpret_cast<float4*>(x_tm + (size_t)row * H_ + threadIdx.x * 4) = v;
}

// ---------------------------------------------------------------------------
// fp32 -> fp16 convert (8 elems/thread), n multiple of 2048
// ---------------------------------------------------------------------------
__global__ __launch_bounds__(256) void conv_half(const float* __restrict__ in,
                                                 _Float16* __restrict__ out, int n)
{
    const int i = (blockIdx.x * 256 + threadIdx.x) * 8;
    if (i + 8 <= n) {
        const float4 v0 = *reinterpret_cast<const float4*>(in + i);
        const float4 v1 = *reinterpret_cast<const float4*>(in + i + 4);
        f16x8 h;
        h[0] = (_Float16)v0.x; h[1] = (_Float16)v0.y;
        h[2] = (_Float16)v0.z; h[3] = (_Float16)v0.w;
        h[4] = (_Float16)v1.x; h[5] = (_Float16)v1.y;
        h[6] = (_Float16)v1.z; h[7] = (_Float16)v1.w;
        *reinterpret_cast<f16x8*>(out + i) = h;
    }
}

// ---------------------------------------------------------------------------
// Tiled fp32 GEMM (kept for xh0 precompute): C[M][N] = A[M][K] * B(K-major)
// ---------------------------------------------------------------------------
__global__ __launch_bounds__(256) void gemm128_kn(const float* __restrict__ A,
                                                  const float* __restrict__ Bm,
                                                  float* __restrict__ C,
                                                  int M, int N, int K)
{
    __shared__ float As[32][132];
    __shared__ float Bs[32][132];

    const int m0 = blockIdx.x * 128;
    const int n0 = blockIdx.y * 128;
    const int tid = threadIdx.x;
    const int tm = (tid >> 4) << 3;
    const int tn = (tid & 15) << 3;

    float acc[8][8];
#pragma unroll
    for (int i = 0; i < 8; ++i)
#pragma unroll
        for (int j = 0; j < 8; ++j) acc[i][j] = 0.0f;

    for (int k0 = 0; k0 < K; k0 += 32) {
#pragma unroll
        for (int i = 0; i < 4; ++i) {
            const int s = tid + (i << 8);
            const int m = s >> 3;
            const int kk = (s & 7) << 2;
            const float4 v = *reinterpret_cast<const float4*>(
                A + (size_t)(m0 + m) * K + k0 + kk);
            As[kk + 0][m] = v.x; As[kk + 1][m] = v.y;
            As[kk + 2][m] = v.z; As[kk + 3][m] = v.w;
        }
#pragma unroll
        for (int i = 0; i < 4; ++i) {
            const int s = tid + (i << 8);
            const int kk = s >> 5;
            const int nn = (s & 31) << 2;
            const float4 v = *reinterpret_cast<const float4*>(
                Bm + (size_t)(k0 + kk) * N + n0 + nn);
            *reinterpret_cast<float4*>(&Bs[kk][nn]) = v;
        }
        __syncthreads();

#pragma unroll
        for (int k = 0; k < 32; ++k) {
            float a[8], bb[8];
            *reinterpret_cast<float4*>(&a[0]) = *reinterpret_cast<const float4*>(&As[k][tm]);
            *reinterpret_cast<float4*>(&a[4]) = *reinterpret_cast<const float4*>(&As[k][tm + 4]);
            *reinterpret_cast<float4*>(&bb[0]) = *reinterpret_cast<const float4*>(&Bs[k][tn]);
            *reinterpret_cast<float4*>(&bb[4]) = *reinterpret_cast<const float4*>(&Bs[k][tn + 4]);
#pragma unroll
            for (int i = 0; i < 8; ++i)
#pragma unroll
                for (int j = 0; j < 8; ++j)
                    acc[i][j] = fmaf(a[i], bb[j], acc[i][j]);
        }
        __syncthreads();
    }

#pragma unroll
    for (int i = 0; i < 8; ++i) {
        const int m = m0 + tm + i;
#pragma unroll
        for (int j = 0; j < 8; j += 4) {
            const int n = n0 + tn + j;
            float4 v;
            v.x = acc[i][j + 0]; v.y = acc[i][j + 1];
            v.z = acc[i][j + 2]; v.w = acc[i][j + 3];
            *reinterpret_cast<float4*>(C + (size_t)m * N + n) = v;
        }
    }
}

// ---------------------------------------------------------------------------
// Fused MI-LSTM timestep (both layers), one block per batch element.
// 1024 threads: thread j owns gate column j of G=1024.
// State (h0,h1,c0,c1) lives in global, block-private [b] slices.
// ---------------------------------------------------------------------------
__global__ __launch_bounds__(1024) void mi_step_fused(
    const float* __restrict__ Uh0,
    const float* __restrict__ Wx1,
    const float* __restrict__ Uh1,
    const float* __restrict__ xh0_t,   // [B][G] for this t
    float* __restrict__ h0g, float* __restrict__ h1g,
    float* __restrict__ c0g, float* __restrict__ c1g,
    _Float16* __restrict__ outsH, int t,
    const float* __restrict__ al0, const float* __restrict__ b10,
    const float* __restrict__ b20, const float* __restrict__ bs0,
    const float* __restrict__ al1, const float* __restrict__ b11,
    const float* __restrict__ b21, const float* __restrict__ bs1)
{
    const int b = blockIdx.x;
    const int j = threadIdx.x;
    __shared__ float h0s[256], h1s[256], xs[256], gs[1024];

    if (j < 256) { h0s[j] = h0g[(b << 8) + j]; h1s[j] = h1g[(b << 8) + j]; }
    __syncthreads();

    // ---- layer 0: hh = h0 @ Uh0 (column j) ----
    float a = 0.f;
    {
        const float* __restrict__ U = Uh0 + j;
#pragma unroll 8
        for (int k = 0; k < 256; ++k) a = fmaf(h0s[k], U[(size_t)k << 10], a);
    }
    {
        const float x = xh0_t[(b << 10) + j];
        gs[j] = al0[j] * x * a + b10[j] * x + b20[j] * a + bs0[j];
    }
    __syncthreads();
    if (j < 256) {
        const float gi = gs[j], gj = gs[j + 256], gf = gs[j + 512], go = gs[j + 768];
        const float cn = c0g[(b << 8) + j] * sigm(gf + 1.0f) + sigm(gi) * tanhf(gj);
        c0g[(b << 8) + j] = cn;
        const float hn = tanhf(cn) * sigm(go);
        h0g[(b << 8) + j] = hn;
        xs[j] = hn;
    }
    __syncthreads();

    // ---- layer 1: xh = x @ Wx1, hh = h1 @ Uh1 (column j) ----
    float xa = 0.f, ha = 0.f;
    {
        const float* __restrict__ W = Wx1 + j;
        const float* __restrict__ U = Uh1 + j;
#pragma unroll 4
        for (int k = 0; k < 256; ++k) {
            xa = fmaf(xs[k],  W[(size_t)k << 10], xa);
            ha = fmaf(h1s[k], U[(size_t)k << 10], ha);
        }
    }
    gs[j] = al1[j] * xa * ha + b11[j] * xa + b21[j] * ha + bs1[j];
    __syncthreads();
    if (j < 256) {
        const float gi = gs[j], gj = gs[j + 256], gf = gs[j + 512], go = gs[j + 768];
        const float cn = c1g[(b << 8) + j] * sigm(gf + 1.0f) + sigm(gi) * tanhf(gj);
        c1g[(b << 8) + j] = cn;
        const float hn = tanhf(cn) * sigm(go);
        h1g[(b << 8) + j] = hn;
        outsH[((size_t)(b * T_ + t) << 8) + j] = (_Float16)hn;
    }
}

// ---------------------------------------------------------------------------
// Projection: C[3200][50000] = A16[3200][256] * B16[50000][256]^T + bias
// fp16 MFMA 16x16x32, 128x128 tile, 4 waves (2x2), BK=64.
// global_load_lds(16B) with pre-swizzled SOURCE + XOR-swizzled ds_read.
// ---------------------------------------------------------------------------
#define PM 128
#define PN 128
#define PK 64

__device__ __forceinline__ void gload_lds16(const void* g, void* l)
{
    __builtin_amdgcn_global_load_lds(
        (const __attribute__((address_space(1))) unsigned int*)g,
        (__attribute__((address_space(3))) unsigned int*)l, 16, 0, 0);
}

__global__ __launch_bounds__(256) void proj_mfma(
    const _Float16* __restrict__ A16,   // [3200][256]
    const _Float16* __restrict__ B16,   // [50000][256]
    const float* __restrict__ bias,     // [50000]
    float* __restrict__ C)              // [3200][50000]
{
    __shared__ __align__(16) _Float16 Asub[PM * PK];
    __shared__ __align__(16) _Float16 Bsub[PN * PK];

    const int tid = threadIdx.x;
    const int l = tid & 63;
    const int w = tid >> 6;             // wave 0..3
    const int wm = w >> 1, wn = w & 1;  // 2x2 wave grid

    const int n0 = blockIdx.x * PN;     // 0..49920
    const int m0 = blockIdx.y * PM;     // 0..3072

    f32x4 acc[4][4] = {};

    for (int k0 = 0; k0 < H_; k0 += PK) {
        // ---- stage A,B tiles: 4 issues each, 16B/thread/issue ----
#pragma unroll
        for (int is = 0; is < 4; ++is) {
            const int i = is * 256 + tid;          // 0..1023
            const int r = i >> 3;                  // 0..127
            const int ch = (i & 7) ^ (r & 7);      // pre-swizzled source chunk
            gload_lds16(A16 + (size_t)(m0 + r) * H_ + k0 + ch * 8, &Asub[i * 8]);
            int n = n0 + r; if (n > V_ - 1) n = V_ - 1;
            gload_lds16(B16 + (size_t)n * H_ + k0 + ch * 8, &Bsub[i * 8]);
        }
        __syncthreads();

#pragma unroll
        for (int ks = 0; ks < 2; ++ks) {
            f16x8 af[4], bf[4];
#pragma unroll
            for (int i = 0; i < 4; ++i) {
                const int r = wm * 64 + i * 16 + (l & 15);
                const int ch = (ks * 4 + (l >> 4)) ^ (r & 7);
                af[i] = *reinterpret_cast<const f16x8*>(&Asub[r * PK + ch * 8]);
            }
#pragma unroll
            for (int jf = 0; jf < 4; ++jf) {
                const int r = wn * 64 + jf * 16 + (l & 15);
                const int ch = (ks * 4 + (l >> 4)) ^ (r & 7);
                bf[jf] = *reinterpret_cast<const f16x8*>(&Bsub[r * PK + ch * 8]);
            }
#pragma unroll
            for (int i = 0; i < 4; ++i)
#pragma unroll
                for (int jf = 0; jf < 4; ++jf)
                    acc[i][jf] = __builtin_amdgcn_mfma_f32_16x16x32_f16(
                        af[i], bf[jf], acc[i][jf], 0, 0, 0);
        }
        __syncthreads();
    }

    // ---- epilogue: D row=(l>>4)*4+r, col=l&15 (m89-verified layout) ----
    const int rb = (l >> 4) << 2;
    const int cl = l & 15;
#pragma unroll
    for (int jf = 0; jf < 4; ++jf) {
        const int col = n0 + wn * 64 + jf * 16 + cl;
        if (col < V_) {
            const float bv = bias[col];
#pragma unroll
            for (int i = 0; i < 4; ++i) {
                const int rowb = m0 + wm * 64 + i * 16 + rb;
#pragma unroll
                for (int r = 0; r < 4; ++r)
                    C[(size_t)(rowb + r) * V_ + col] = acc[i][jf][r] + bv;
            }
        }
    }
}

// ---------------------------------------------------------------------------
extern "C" void kernel_launch(void* const* d_in, const int* in_sizes, int n_in,
                              void* d_out, int out_size, void* d_ws, size_t ws_size,
                              hipStream_t stream)
{
    const int*   idx   = (const int*)  d_in[0];
    const float* emb   = (const float*)d_in[1];
    const float* Wx    = (const float*)d_in[2];   // [2][256][1024]
    const float* Uh    = (const float*)d_in[3];   // [2][256][1024]
    const float* alpha = (const float*)d_in[4];   // [2][1024]
    const float* b1    = (const float*)d_in[5];
    const float* b2    = (const float*)d_in[6];
    const float* bsv   = (const float*)d_in[7];
    const float* sw    = (const float*)d_in[8];   // [50000][256]
    const float* sb    = (const float*)d_in[9];   // [50000]
    float* out = (float*)d_out;

    // workspace layout (bytes)
    char* wsb = (char*)d_ws;
    float*    x_tm  = (float*)   (wsb);                 //  3,276,800 B
    float*    xh0   = (float*)   (wsb + 3276800);       // 13,107,200 B
    _Float16* outsH = (_Float16*)(wsb + 16384000);      //  1,638,400 B
    float*    h0g   = (float*)   (wsb + 18022400);      //     65,536 B
    float*    h1g   = (float*)   (wsb + 18088960 - 1024);  // = 18,087,936
    float*    c0g   = (float*)   (wsb + 18153472);
    float*    c1g   = (float*)   (wsb + 18219008);
    _Float16* w16   = (_Float16*)(wsb + 18284544);      // 25,600,000 B

    // zero the recurrent state (h0g..c1g contiguous, 4 * 64KiB)
    hipMemsetAsync(h0g, 0, (size_t)4 * B_ * H_ * sizeof(float), stream);

    // softmax weights -> fp16
    conv_half<<<(V_ * H_) / 2048, 256, 0, stream>>>(sw, w16, V_ * H_);

    // 1) embedding gather (time-major)
    embed_k<<<T_ * B_, 64, 0, stream>>>(idx, emb, x_tm);

    // 2) xh for layer 0, all timesteps: [3200,256] @ [256,1024]
    {
        dim3 grid(3200 / 128, G_ / 128);
        gemm128_kn<<<grid, 256, 0, stream>>>(x_tm, Wx, xh0, 3200, G_, H_);
    }

    // 3) recurrence: one fused dispatch per timestep
    const float* Wx1 = Wx + (size_t)H_ * G_;
    const float* Uh0 = Uh;
    const float* Uh1 = Uh + (size_t)H_ * G_;
    for (int t = 0; t < T_; ++t) {
        mi_step_fused<<<B_, 1024, 0, stream>>>(
            Uh0, Wx1, Uh1, xh0 + (size_t)t * B_ * G_,
            h0g, h1g, c0g, c1g, outsH, t,
            alpha, b1, b2, bsv,
            alpha + G_, b1 + G_, b2 + G_, bsv + G_);
    }

    // 4) logits = outsH @ w16^T + sb : fp16 MFMA
    {
        dim3 grid((V_ + PN - 1) / PN, 3200 / PM);   // (391, 25)
        proj_mfma<<<grid, 256, 0, stream>>>(outsH, w16, sb, out);
    }
}

// Round 4
// 1015.551 us; speedup vs baseline: 3.3406x; 1.7325x over previous
//
#include <hip/hip_runtime.h>
#include <hip/hip_bf16.h>
#include <math.h>

// Problem constants
#define B_ 64
#define T_ 50
#define H_ 256
#define G_ 1024
#define V_ 50000

using f16x8 = __attribute__((ext_vector_type(8))) _Float16;
using f16x2 = __attribute__((ext_vector_type(2))) _Float16;
using f32x4 = __attribute__((ext_vector_type(4))) float;

__device__ __forceinline__ float sigm(float x) { return 1.0f / (1.0f + expf(-x)); }

#if __has_builtin(__builtin_amdgcn_fdot2)
#define FDOT2(a, b, c) __builtin_amdgcn_fdot2((a), (b), (c), false)
#else
__device__ __forceinline__ float fdot2_emul(f16x2 a, f16x2 b, float c)
{ return fmaf((float)a[0], (float)b[0], fmaf((float)a[1], (float)b[1], c)); }
#define FDOT2 fdot2_emul
#endif

// ---------------------------------------------------------------------------
// Embedding gather: x_tm[t*B + b][h] = emb[idx[b*T + t]][h]   (time-major)
// ---------------------------------------------------------------------------
__global__ __launch_bounds__(64) void embed_k(const int* __restrict__ idx,
                                              const float* __restrict__ emb,
                                              float* __restrict__ x_tm)
{
    const int row = blockIdx.x;          // t*B + b
    const int b = row & (B_ - 1);
    const int t = row >> 6;              // /B_
    const int id = idx[b * T_ + t];
    const float4 v = *reinterpret_cast<const float4*>(emb + (size_t)id * H_ + threadIdx.x * 4);
    *reinterpret_cast<float4*>(x_tm + (size_t)row * H_ + threadIdx.x * 4) = v;
}

// ---------------------------------------------------------------------------
// fp32 -> fp16 convert (8 elems/thread), n multiple of 2048
// ---------------------------------------------------------------------------
__global__ __launch_bounds__(256) void conv_half(const float* __restrict__ in,
                                                 _Float16* __restrict__ out, int n)
{
    const int i = (blockIdx.x * 256 + threadIdx.x) * 8;
    if (i + 8 <= n) {
        const float4 v0 = *reinterpret_cast<const float4*>(in + i);
        const float4 v1 = *reinterpret_cast<const float4*>(in + i + 4);
        f16x8 h;
        h[0] = (_Float16)v0.x; h[1] = (_Float16)v0.y;
        h[2] = (_Float16)v0.z; h[3] = (_Float16)v0.w;
        h[4] = (_Float16)v1.x; h[5] = (_Float16)v1.y;
        h[6] = (_Float16)v1.z; h[7] = (_Float16)v1.w;
        *reinterpret_cast<f16x8*>(out + i) = h;
    }
}

// ---------------------------------------------------------------------------
// Pack recurrence weights [256][1024] fp32 -> [128][1024] half2 (k-pairs)
// grid (128, 3): blockIdx.y selects {Uh0, Wx1, Uh1}
// ---------------------------------------------------------------------------
__global__ __launch_bounds__(256) void pack_w_half2(const float* __restrict__ Uh0,
                                                    const float* __restrict__ Wx1,
                                                    const float* __restrict__ Uh1,
                                                    f16x2* __restrict__ up0,
                                                    f16x2* __restrict__ wx1p,
                                                    f16x2* __restrict__ uh1p)
{
    const int k2 = blockIdx.x;           // 0..127
    const int which = blockIdx.y;        // 0..2
    const float* __restrict__ src = (which == 0) ? Uh0 : (which == 1) ? Wx1 : Uh1;
    f16x2* __restrict__ dst = (which == 0) ? up0 : (which == 1) ? wx1p : uh1p;
#pragma unroll
    for (int i = 0; i < 4; ++i) {
        const int j = threadIdx.x + (i << 8);
        const float lo = src[(size_t)(2 * k2) * G_ + j];
        const float hi = src[(size_t)(2 * k2 + 1) * G_ + j];
        f16x2 p; p[0] = (_Float16)lo; p[1] = (_Float16)hi;
        dst[(size_t)k2 * G_ + j] = p;
    }
}

// ---------------------------------------------------------------------------
// Tiled fp32 GEMM (xh0 precompute): C[M][N] = A[M][K] * B(K-major)
// ---------------------------------------------------------------------------
__global__ __launch_bounds__(256) void gemm128_kn(const float* __restrict__ A,
                                                  const float* __restrict__ Bm,
                                                  float* __restrict__ C,
                                                  int M, int N, int K)
{
    __shared__ float As[32][132];
    __shared__ float Bs[32][132];

    const int m0 = blockIdx.x * 128;
    const int n0 = blockIdx.y * 128;
    const int tid = threadIdx.x;
    const int tm = (tid >> 4) << 3;
    const int tn = (tid & 15) << 3;

    float acc[8][8];
#pragma unroll
    for (int i = 0; i < 8; ++i)
#pragma unroll
        for (int j = 0; j < 8; ++j) acc[i][j] = 0.0f;

    for (int k0 = 0; k0 < K; k0 += 32) {
#pragma unroll
        for (int i = 0; i < 4; ++i) {
            const int s = tid + (i << 8);
            const int m = s >> 3;
            const int kk = (s & 7) << 2;
            const float4 v = *reinterpret_cast<const float4*>(
                A + (size_t)(m0 + m) * K + k0 + kk);
            As[kk + 0][m] = v.x; As[kk + 1][m] = v.y;
            As[kk + 2][m] = v.z; As[kk + 3][m] = v.w;
        }
#pragma unroll
        for (int i = 0; i < 4; ++i) {
            const int s = tid + (i << 8);
            const int kk = s >> 5;
            const int nn = (s & 31) << 2;
            const float4 v = *reinterpret_cast<const float4*>(
                Bm + (size_t)(k0 + kk) * N + n0 + nn);
            *reinterpret_cast<float4*>(&Bs[kk][nn]) = v;
        }
        __syncthreads();

#pragma unroll
        for (int k = 0; k < 32; ++k) {
            float a[8], bb[8];
            *reinterpret_cast<float4*>(&a[0]) = *reinterpret_cast<const float4*>(&As[k][tm]);
            *reinterpret_cast<float4*>(&a[4]) = *reinterpret_cast<const float4*>(&As[k][tm + 4]);
            *reinterpret_cast<float4*>(&bb[0]) = *reinterpret_cast<const float4*>(&Bs[k][tn]);
            *reinterpret_cast<float4*>(&bb[4]) = *reinterpret_cast<const float4*>(&Bs[k][tn + 4]);
#pragma unroll
            for (int i = 0; i < 8; ++i)
#pragma unroll
                for (int j = 0; j < 8; ++j)
                    acc[i][j] = fmaf(a[i], bb[j], acc[i][j]);
        }
        __syncthreads();
    }

#pragma unroll
    for (int i = 0; i < 8; ++i) {
        const int m = m0 + tm + i;
#pragma unroll
        for (int j = 0; j < 8; j += 4) {
            const int n = n0 + tn + j;
            float4 v;
            v.x = acc[i][j + 0]; v.y = acc[i][j + 1];
            v.z = acc[i][j + 2]; v.w = acc[i][j + 3];
            *reinterpret_cast<float4*>(C + (size_t)m * N + n) = v;
        }
    }
}

// ---------------------------------------------------------------------------
// Persistent MI-LSTM recurrence: one block per batch element, all T steps.
// 1024 threads; thread j owns gate column j. State in LDS; weights fp16
// half2-packed, read from L2 every step via v_dot2_f32_f16.
// ---------------------------------------------------------------------------
__global__ __launch_bounds__(1024) void mi_persist(
    const f16x2* __restrict__ up0,     // [128][1024]
    const f16x2* __restrict__ wx1p,    // [128][1024]
    const f16x2* __restrict__ uh1p,    // [128][1024]
    const float* __restrict__ xh0,     // [T*B][G]
    _Float16* __restrict__ outsH,      // [B*T][H]
    const float* __restrict__ alpha,   // [2][1024]
    const float* __restrict__ b1,
    const float* __restrict__ b2,
    const float* __restrict__ bsv)
{
    const int b = blockIdx.x;
    const int j = threadIdx.x;

    __shared__ __align__(16) _Float16 h0h[256];
    __shared__ __align__(16) _Float16 h1h[256];
    __shared__ float gs[1024];
    __shared__ float c0s[256], c1s[256];

    if (j < 256) {
        h0h[j] = (_Float16)0.f; h1h[j] = (_Float16)0.f;
        c0s[j] = 0.f; c1s[j] = 0.f;
    }
    // per-thread gate params
    const float a0v = alpha[j],      b10v = b1[j],      b20v = b2[j],      bs0v = bsv[j];
    const float a1v = alpha[G_ + j], b11v = b1[G_ + j], b21v = b2[G_ + j], bs1v = bsv[G_ + j];
    __syncthreads();

    const f16x2* __restrict__ h02 = reinterpret_cast<const f16x2*>(h0h);
    const f16x2* __restrict__ h12 = reinterpret_cast<const f16x2*>(h1h);

    for (int t = 0; t < T_; ++t) {
        // ---- layer 0: a = (h0 @ Uh0)[j] ----
        float a = 0.f;
#pragma unroll 8
        for (int k2 = 0; k2 < 128; ++k2)
            a = FDOT2(h02[k2], up0[(size_t)k2 * G_ + j], a);
        const float x = xh0[((size_t)(t * B_ + b) << 10) + j];
        gs[j] = a0v * x * a + b10v * x + b20v * a + bs0v;
        __syncthreads();

        if (j < 256) {
            const float gi = gs[j], gj = gs[j + 256], gf = gs[j + 512], go = gs[j + 768];
            const float cn = c0s[j] * sigm(gf + 1.0f) + sigm(gi) * tanhf(gj);
            c0s[j] = cn;
            h0h[j] = (_Float16)(tanhf(cn) * sigm(go));
        }
        __syncthreads();

        // ---- layer 1: xa = (h0new @ Wx1)[j], ha = (h1 @ Uh1)[j] ----
        float xa = 0.f, ha = 0.f;
#pragma unroll 4
        for (int k2 = 0; k2 < 128; ++k2) {
            xa = FDOT2(h02[k2], wx1p[(size_t)k2 * G_ + j], xa);
            ha = FDOT2(h12[k2], uh1p[(size_t)k2 * G_ + j], ha);
        }
        gs[j] = a1v * xa * ha + b11v * xa + b21v * ha + bs1v;
        __syncthreads();

        if (j < 256) {
            const float gi = gs[j], gj = gs[j + 256], gf = gs[j + 512], go = gs[j + 768];
            const float cn = c1s[j] * sigm(gf + 1.0f) + sigm(gi) * tanhf(gj);
            c1s[j] = cn;
            const float hn = tanhf(cn) * sigm(go);
            h1h[j] = (_Float16)hn;
            outsH[((size_t)(b * T_ + t) << 8) + j] = (_Float16)hn;
        }
        __syncthreads();
    }
}

// ---------------------------------------------------------------------------
// Projection: C[3200][50000] = A16[3200][256] * B16[50000][256]^T + bias
// fp16 MFMA 16x16x32, 128x128 tile, 4 waves (2x2), BK=64.
// global_load_lds(16B) with pre-swizzled SOURCE + XOR-swizzled ds_read.
// ---------------------------------------------------------------------------
#define PM 128
#define PN 128
#define PK 64

__device__ __forceinline__ void gload_lds16(const void* g, void* l)
{
    __builtin_amdgcn_global_load_lds(
        (const __attribute__((address_space(1))) unsigned int*)g,
        (__attribute__((address_space(3))) unsigned int*)l, 16, 0, 0);
}

__global__ __launch_bounds__(256) void proj_mfma(
    const _Float16* __restrict__ A16,   // [3200][256]
    const _Float16* __restrict__ B16,   // [50000][256]
    const float* __restrict__ bias,     // [50000]
    float* __restrict__ C)              // [3200][50000]
{
    __shared__ __align__(16) _Float16 Asub[PM * PK];
    __shared__ __align__(16) _Float16 Bsub[PN * PK];

    const int tid = threadIdx.x;
    const int l = tid & 63;
    const int w = tid >> 6;             // wave 0..3
    const int wm = w >> 1, wn = w & 1;  // 2x2 wave grid

    const int n0 = blockIdx.x * PN;     // 0..49920
    const int m0 = blockIdx.y * PM;     // 0..3072

    f32x4 acc[4][4] = {};

    for (int k0 = 0; k0 < H_; k0 += PK) {
        // ---- stage A,B tiles: 4 issues each, 16B/thread/issue ----
#pragma unroll
        for (int is = 0; is < 4; ++is) {
            const int i = is * 256 + tid;          // 0..1023
            const int r = i >> 3;                  // 0..127
            const int ch = (i & 7) ^ (r & 7);      // pre-swizzled source chunk
            gload_lds16(A16 + (size_t)(m0 + r) * H_ + k0 + ch * 8, &Asub[i * 8]);
            int n = n0 + r; if (n > V_ - 1) n = V_ - 1;
            gload_lds16(B16 + (size_t)n * H_ + k0 + ch * 8, &Bsub[i * 8]);
        }
        __syncthreads();

#pragma unroll
        for (int ks = 0; ks < 2; ++ks) {
            f16x8 af[4], bf[4];
#pragma unroll
            for (int i = 0; i < 4; ++i) {
                const int r = wm * 64 + i * 16 + (l & 15);
                const int ch = (ks * 4 + (l >> 4)) ^ (r & 7);
                af[i] = *reinterpret_cast<const f16x8*>(&Asub[r * PK + ch * 8]);
            }
#pragma unroll
            for (int jf = 0; jf < 4; ++jf) {
                const int r = wn * 64 + jf * 16 + (l & 15);
                const int ch = (ks * 4 + (l >> 4)) ^ (r & 7);
                bf[jf] = *reinterpret_cast<const f16x8*>(&Bsub[r * PK + ch * 8]);
            }
#pragma unroll
            for (int i = 0; i < 4; ++i)
#pragma unroll
                for (int jf = 0; jf < 4; ++jf)
                    acc[i][jf] = __builtin_amdgcn_mfma_f32_16x16x32_f16(
                        af[i], bf[jf], acc[i][jf], 0, 0, 0);
        }
        __syncthreads();
    }

    // ---- epilogue: D row=(l>>4)*4+r, col=l&15 (m89-verified layout) ----
    const int rb = (l >> 4) << 2;
    const int cl = l & 15;
#pragma unroll
    for (int jf = 0; jf < 4; ++jf) {
        const int col = n0 + wn * 64 + jf * 16 + cl;
        if (col < V_) {
            const float bv = bias[col];
#pragma unroll
            for (int i = 0; i < 4; ++i) {
                const int rowb = m0 + wm * 64 + i * 16 + rb;
#pragma unroll
                for (int r = 0; r < 4; ++r)
                    C[(size_t)(rowb + r) * V_ + col] = acc[i][jf][r] + bv;
            }
        }
    }
}

// ---------------------------------------------------------------------------
extern "C" void kernel_launch(void* const* d_in, const int* in_sizes, int n_in,
                              void* d_out, int out_size, void* d_ws, size_t ws_size,
                              hipStream_t stream)
{
    const int*   idx   = (const int*)  d_in[0];
    const float* emb   = (const float*)d_in[1];
    const float* Wx    = (const float*)d_in[2];   // [2][256][1024]
    const float* Uh    = (const float*)d_in[3];   // [2][256][1024]
    const float* alpha = (const float*)d_in[4];   // [2][1024]
    const float* b1    = (const float*)d_in[5];
    const float* b2    = (const float*)d_in[6];
    const float* bsv   = (const float*)d_in[7];
    const float* sw    = (const float*)d_in[8];   // [50000][256]
    const float* sb    = (const float*)d_in[9];   // [50000]
    float* out = (float*)d_out;

    // workspace layout (bytes)
    char* wsb = (char*)d_ws;
    float*    x_tm  = (float*)   (wsb);                 //  3,276,800
    float*    xh0   = (float*)   (wsb + 3276800);       // 13,107,200
    _Float16* outsH = (_Float16*)(wsb + 16384000);      //  1,638,400
    _Float16* w16   = (_Float16*)(wsb + 18022400);      // 25,600,000
    f16x2*    up0   = (f16x2*)   (wsb + 43622400);      //    524,288
    f16x2*    wx1p  = (f16x2*)   (wsb + 44146688);      //    524,288
    f16x2*    uh1p  = (f16x2*)   (wsb + 44670976);      //    524,288  (end ~45.2 MB)

    const float* Wx1 = Wx + (size_t)H_ * G_;
    const float* Uh0 = Uh;
    const float* Uh1 = Uh + (size_t)H_ * G_;

    // 0) pack recurrence weights to half2
    {
        dim3 grid(128, 3);
        pack_w_half2<<<grid, 256, 0, stream>>>(Uh0, Wx1, Uh1, up0, wx1p, uh1p);
    }

    // softmax weights -> fp16
    conv_half<<<(V_ * H_) / 2048, 256, 0, stream>>>(sw, w16, V_ * H_);

    // 1) embedding gather (time-major)
    embed_k<<<T_ * B_, 64, 0, stream>>>(idx, emb, x_tm);

    // 2) xh for layer 0, all timesteps: [3200,256] @ [256,1024]
    {
        dim3 grid(3200 / 128, G_ / 128);
        gemm128_kn<<<grid, 256, 0, stream>>>(x_tm, Wx, xh0, 3200, G_, H_);
    }

    // 3) recurrence: single persistent dispatch
    mi_persist<<<B_, 1024, 0, stream>>>(up0, wx1p, uh1p, xh0, outsH,
                                        alpha, b1, b2, bsv);

    // 4) logits = outsH @ w16^T + sb : fp16 MFMA
    {
        dim3 grid((V_ + PN - 1) / PN, 3200 / PM);   // (391, 25)
        proj_mfma<<<grid, 256, 0, stream>>>(outsH, w16, sb, out);
    }
}